// Round 5
// baseline (284.461 us; speedup 1.0000x reference)
//
#include <hip/hip_runtime.h>

// RoiPooling via integral image, fused single-pass scan:
//  fusedScanK: fm (C,H,W) -> S'[cb][y][x][16] blocked-channel-last; each
//              y-chunk of 8 rows holds a LOCAL 2D integral (row-scan full-x,
//              col-scan local to chunk). Zero borders written inline.
//  offsetK   : OP'[cb][k][x][16] = fp64 prefix over the 31 chunk totals.
//  gatherK   : corner value = S_local[ry][rx] + OP[chunk(ry)][rx]; 9-corner
//              per-ROI gather, 4-corner difference per patch.
//
// Round 4 -> 5: 16 channels/block (was 32). Falsified so far for the scan:
// occupancy-within-block (2x waves, null), barrier vmcnt drain (removed,
// null), LDS conflicts (3.1M -> 0, null), DRAM write scatter (1KB-contig
// stores, null). Untested lever: INDEPENDENT barrier groups per CU. All
// rounds had exactly 2 blocks/CU (LDS 66.5KB), each internally phase-locked
// by the per-y barrier -> when both sit in the same phase, a memory pipe
// idles. Halving LDS to 33.3KB gives 4 independent blocks/CU (32 waves/CU),
// doubling phase-interleaved streams. Addressing/tile change only: per-
// channel arithmetic order identical, output bit-identical.
//
// ws layout (floats):
//   S  @ 0          size 32*257*257*16 = 33,817,088  (135.3 MB)
//   OP @ 33817088   size 32*33*257*16  =  4,342,272  ( 17.4 MB)

#define CHN 512
#define HD  256
#define WD  256
#define SP  257
#define YC  8                 // rows per y-chunk
#define NK  32                // number of y-chunks
#define CB  16                // channels per block / innermost S dim
#define OP_OFF 33817088UL

#define SIDX(cb, y, x)   ((((size_t)(cb) * SP + (y)) * SP + (x)) * CB)
#define OPIDX(cb, kk, x) ((((size_t)(cb) * 33 + (kk)) * SP + (x)) * CB)

// Raw barrier: LDS-drain only, NO vmcnt(0) (keeps prefetch loads + S stores
// in flight across y-steps). lgkmcnt(0) drains this wave's ds_writes
// (producer visibility) and ds_reads (WAR safety for y+2 buffer reuse).
// Trailing empty asm: s_barrier is IntrNoMem at IR level; fence stops LLVM
// hoisting post-barrier LDS reads above it. Zero cost.
#define BAR() do { asm volatile("s_waitcnt lgkmcnt(0)" ::: "memory"); \
                   __builtin_amdgcn_s_barrier(); \
                   asm volatile("" ::: "memory"); } while (0)

// ---------------- fused scan: fm -> S' (chunk-local integral) --------------
// Block 512 thr (8 waves); tile = 16 c x 256 x x 8 y. Grid (32 cb, 32 k) =
// 1024 blocks = 4 blocks/CU (LDS 33.3 KB x4 = 133 KB), 32 waves/CU.
// Per y: wave scans 2 channels (full 256-x shuffle prefix), LDS transpose
// (double buffered, ONE raw barrier per y), fp32 col-accumulate in store
// layout, 1KB-contiguous per-wave stores.
// LDS XOR swizzle col ^= 4*(row>>2) both sides (else store-phase reads are a
// deterministic 4-way conflict; swizzled reads are 2-way max = free, m136).
__global__ __launch_bounds__(512, 4) void fusedScanK(const float* __restrict__ fm,
                                                     float* __restrict__ S) {
    __shared__ float tile[2][CB][260];   // 260 pad: 16B-aligned rows
    const int t = threadIdx.x, lane = t & 63, w = t >> 6;   // w = wave 0..7
    const int cb = blockIdx.x;           // channel block (16 ch), 0..31
    const int c0 = cb * CB;
    const int k  = blockIdx.y;
    const int y0 = k * YC;

    const int cg = t & 3;                // store: 4-channel group (4 groups = 16 ch)
    const int x8 = t >> 2;               // store: x mod 128
    const float4 z4 = make_float4(0.f, 0.f, 0.f, 0.f);

    if (k == 0) {                        // y=0 border row, x=0..255 (x=256 never read)
        #pragma unroll
        for (int it = 0; it < 2; ++it) {
            const int lin = it * 512 + t;
            const int cgg = lin & 3, x = lin >> 2;
            *(float4*)(S + SIDX(cb, 0, x) + 4 * cgg) = z4;
        }
    }

    float4 cur[2], nxt[2];
    #pragma unroll
    for (int j = 0; j < 2; ++j)
        cur[j] = *(const float4*)(fm + ((size_t)(c0 + w * 2 + j) << 16)
                                     + (size_t)y0 * 256 + 4 * lane);

    float4 acc[2];
    #pragma unroll
    for (int m = 0; m < 2; ++m) acc[m] = z4;

    const int rxor = 4 * cg;             // read swizzle key (rows 4cg+r -> row>>2 == cg)

    for (int y = 0; y < YC; ++y) {
        const int buf = y & 1;
        if (y < YC - 1) {                // prefetch next row-block (stays in
            #pragma unroll               //  flight across the raw barrier)
            for (int j = 0; j < 2; ++j)
                nxt[j] = *(const float4*)(fm + ((size_t)(c0 + w * 2 + j) << 16)
                                             + (size_t)(y0 + y + 1) * 256 + 4 * lane);
        }
        // row scan: wave w handles channels w*2, w*2+1, full 256-x per row
        #pragma unroll
        for (int j = 0; j < 2; ++j) {
            const float4 v = cur[j];
            const float local = ((v.x + v.y) + v.z) + v.w;
            float s = local;
            #pragma unroll
            for (int d = 1; d < 64; d <<= 1) {
                float u = __shfl_up(s, d, 64);
                if (lane >= d) s += u;
            }
            const float e = s - local;   // exclusive lane prefix
            float4 p;
            p.x = e   + v.x;
            p.y = p.x + v.y;
            p.z = p.y + v.z;
            p.w = p.z + v.w;
            const int row  = w * 2 + j;
            const int wcol = (4 * lane) ^ (4 * (row >> 2));  // swizzled write col
            *(float4*)&tile[buf][row][wcol] = p;
        }
        BAR();
        // col-accumulate + store: per wave, 16 consecutive x * 64B = 1KB
        // contiguous per store instruction; block's 8 rows one dense region.
        const size_t rowb = SIDX(cb, y0 + y + 1, 0);
        #pragma unroll
        for (int m = 0; m < 2; ++m) {
            const int x = x8 + 128 * m;
            const int xs = x ^ rxor;     // swizzled read column (same for all 4 rows)
            float4 a = acc[m];
            a.x += tile[buf][4 * cg + 0][xs];
            a.y += tile[buf][4 * cg + 1][xs];
            a.z += tile[buf][4 * cg + 2][xs];
            a.w += tile[buf][4 * cg + 3][xs];
            acc[m] = a;
            *(float4*)(S + rowb + (size_t)(x + 1) * CB + 4 * cg) = a;
        }
        if (t < 4)                       // x=0 border for this row (64B)
            *(float4*)(S + rowb + 4 * t) = z4;
        #pragma unroll
        for (int j = 0; j < 2; ++j) cur[j] = nxt[j];
        // no second barrier: next y writes the other LDS buffer; y+2's reuse
        // of this buffer is ordered by the y+1 barrier (lgkmcnt(0) there
        // drains this wave's reads before it signals).
    }
}

// ---------------- offsetK: fp64 prefix of chunk totals ---------------------
// OP'[cb][k][x][16], k=0..32; OP[0]=OP[1]=0; OP[k>=2] = sum of chunk totals
// 0..k-2. Chunk j total = S'[cb][8(j+1)][x][..] (last local row of chunk j).
__global__ __launch_bounds__(256) void offsetK(const float* __restrict__ S,
                                               float* __restrict__ OP) {
    const int gid = blockIdx.x * 256 + threadIdx.x;   // 0 .. 131583 exactly
    const int cc = gid & (CB - 1);
    const int xr = gid >> 4;           // 0..8223
    const int x  = xr % SP;            // 0..256
    const int cb = xr / SP;            // 0..31
    OP[OPIDX(cb, 0, x) + cc] = 0.0f;
    OP[OPIDX(cb, 1, x) + cc] = 0.0f;
    double run = 0.0;
    #pragma unroll
    for (int j = 0; j < NK - 1; ++j) {
        run += (double)S[SIDX(cb, YC * (j + 1), x) + cc];
        OP[OPIDX(cb, j + 2, x) + cc] = (float)run;
    }
}

// ---------------- gatherK: per-ROI 9-corner gather with offset add ---------
__global__ __launch_bounds__(256) void gatherK(const float* __restrict__ S,
                                              const float* __restrict__ OP,
                                              const float* __restrict__ roi,
                                              float* __restrict__ out,
                                              float* __restrict__ maskOut,
                                              int N) {
    const int n = blockIdx.x;
    const float xmin = roi[4 * n + 0];
    const float ymin = roi[4 * n + 1];
    const float xmax = roi[4 * n + 2];
    const float ymax = roi[4 * n + 3];

    // Replicate np fp32 op order exactly (no fma contraction).
    const float wsv = __fdiv_rn(__fsub_rn(xmax, xmin), 2.0f);
    const float hsv = __fdiv_rn(__fsub_rn(ymax, ymin), 2.0f);
    const float ax1 = __fadd_rn(xmin, wsv);
    const float ay1 = __fadd_rn(ymin, hsv);
    const float lim = (float)(WD - 1);

    int rx[3], ry[3];
    rx[0] = (int)fminf(fmaxf(rintf(xmin), 0.0f), lim);
    rx[1] = (int)fminf(fmaxf(rintf(ax1), 0.0f), lim);
    rx[2] = (int)fminf(fmaxf(rintf(__fadd_rn(ax1, wsv)), 0.0f), lim);
    ry[0] = (int)fminf(fmaxf(rintf(ymin), 0.0f), lim);
    ry[1] = (int)fminf(fmaxf(rintf(ay1), 0.0f), lim);
    ry[2] = (int)fminf(fmaxf(rintf(__fadd_rn(ay1, hsv)), 0.0f), lim);

    const int t = threadIdx.x;            // c-pair: channels 2t, 2t+1
    const int cbb = t >> 3;               // channel block 0..31
    const int cc  = (t & 7) * 2;          // within-block channel 0..14 (even)
    float2 g[3][3];
    #pragma unroll
    for (int j = 0; j < 3; ++j) {
        const int kk = (ry[j] + YC - 1) >> 3;   // chunk-offset row in OP
        #pragma unroll
        for (int i = 0; i < 3; ++i) {
            const float2 l = *(const float2*)(S  + SIDX(cbb, ry[j], rx[i]) + cc);
            const float2 o = *(const float2*)(OP + OPIDX(cbb, kk, rx[i]) + cc);
            g[j][i] = make_float2(l.x + o.x, l.y + o.y);
        }
    }

    float m[4];
    #pragma unroll
    for (int p = 0; p < 4; ++p) {
        const int ix = p & 1, iy = p >> 1;
        const int cw = rx[ix + 1] - rx[ix];
        const int ch = ry[iy + 1] - ry[iy];
        const int maskv = (cw >= 1 && ch >= 1) ? 1 : 0;
        int areai = cw * ch; if (areai < 1) areai = 1;
        const float areaf = (float)areai;
        const float maskf = (float)maskv;
        m[p] = maskf;

        const float2 s11 = g[iy + 1][ix + 1];
        const float2 s01 = g[iy][ix + 1];
        const float2 s10 = g[iy + 1][ix];
        const float2 s00 = g[iy][ix];
        float2 o;  // reference order: ((S11 - S01) - S10) + S00, /area, *mask
        o.x = __fdiv_rn(((s11.x - s01.x) - s10.x) + s00.x, areaf) * maskf;
        o.y = __fdiv_rn(((s11.y - s01.y) - s10.y) + s00.y, areaf) * maskf;
        *(float2*)(out + ((size_t)p * N + n) * CHN + 2 * t) = o;
    }
    if (t < 4) maskOut[(size_t)t * N + n] = m[t];
}

// ---------------------------------------------------------------------------
extern "C" void kernel_launch(void* const* d_in, const int* in_sizes, int n_in,
                              void* d_out, int out_size, void* d_ws, size_t ws_size,
                              hipStream_t stream) {
    const float* fm  = (const float*)d_in[0];
    const float* roi = (const float*)d_in[1];
    // d_in[2] = patch_num (always 4 here); pe=2 hardcoded.

    const int N = in_sizes[1] / 4;     // 4096
    const int B = 4 * N;               // 16384

    float* S  = (float*)d_ws;
    float* OP = (float*)d_ws + OP_OFF;
    float* out     = (float*)d_out;
    float* maskOut = out + (size_t)B * CHN;

    dim3 gF(CHN / CB, NK);             // 32 x 32 = 1024 blocks, 4/CU
    fusedScanK<<<gF, 512, 0, stream>>>(fm, S);

    offsetK<<<(32 * SP * CB) / 256, 256, 0, stream>>>(S, OP);   // 514 blocks

    gatherK<<<N, 256, 0, stream>>>(S, OP, roi, out, maskOut, N);
}

// Round 7
// 270.077 us; speedup vs baseline: 1.0533x; 1.0533x over previous
//
#include <hip/hip_runtime.h>

// RoiPooling via integral image, fused single-pass scan:
//  fusedScanK: fm (C,H,W) -> S'[cb][y][x][32] blocked-channel-last; each
//              y-chunk of 8 rows holds a LOCAL 2D integral (row-scan full-x,
//              col-scan local to chunk). Zero borders written inline.
//  offsetK   : OP'[cb][k][x][32] = fp64 prefix over the 31 chunk totals.
//  gatherK   : corner value = S_local[ry][rx] + OP[chunk(ry)][rx]; 9-corner
//              per-ROI gather, 4-corner difference per patch.
//
// Round 5 -> 6 (retry; r6 was a compile error — __builtin_nontemporal_store
// rejects HIP_vector_type float4; use clang ext_vector_type): EXACT round-4
// config (CB=32, 2 blocks/CU — its best) with ONE change: S stores are
// non-temporal. Falsified for the scan so far: wave count, barrier vmcnt
// drain, LDS conflicts, DRAM write scatter, independent block streams. All
// variants sit at 2.2-2.4 TB/s while the 537MB harness fill hits 6.4 TB/s in
// the same stream. Difference: fill (2x L3) STREAMS; our 132MB S fits L3 ->
// write-ALLOCATE path. Theory: L3 write-allocate ingress caps ~2.4 TB/s; nt
// stores bypass allocation -> streaming rate. Cache hint only: output
// bit-identical.
//
// ws layout (floats):
//   S  @ 0          size 16*257*257*32 = 33,817,088  (135.3 MB)
//   OP @ 33817088   size 16*33*257*32  =  4,342,272  ( 17.4 MB)

#define CHN 512
#define HD  256
#define WD  256
#define SP  257
#define YC  8                 // rows per y-chunk
#define NK  32                // number of y-chunks
#define CB  32                // channels per block / innermost S dim
#define OP_OFF 33817088UL

#define SIDX(cb, y, x)   ((((size_t)(cb) * SP + (y)) * SP + (x)) * CB)
#define OPIDX(cb, kk, x) ((((size_t)(cb) * 33 + (kk)) * SP + (x)) * CB)

typedef float f32x4 __attribute__((ext_vector_type(4)));

__device__ __forceinline__ void ntst4(float* p, float4 v) {
    f32x4 u;
    u.x = v.x; u.y = v.y; u.z = v.z; u.w = v.w;
    __builtin_nontemporal_store(u, (f32x4*)p);
}

// Raw barrier: LDS-drain only, NO vmcnt(0) (keeps prefetch loads + S stores
// in flight across y-steps). lgkmcnt(0) drains this wave's ds_writes
// (producer visibility) and ds_reads (WAR safety for y+2 buffer reuse).
// Trailing empty asm: s_barrier is IntrNoMem at IR level; fence stops LLVM
// hoisting post-barrier LDS reads above it. Zero cost.
#define BAR() do { asm volatile("s_waitcnt lgkmcnt(0)" ::: "memory"); \
                   __builtin_amdgcn_s_barrier(); \
                   asm volatile("" ::: "memory"); } while (0)

// ---------------- fused scan: fm -> S' (chunk-local integral) --------------
// Block 512 thr (8 waves); tile = 32 c x 256 x x 8 y. Grid (16 cb, 32 k) =
// 512 blocks = 2 blocks/CU (LDS 66.5 KB x2 = 133 KB), 16 waves/CU.
// LDS XOR swizzle col ^= 4*(row>>2): store-phase reads were a 4-way bank
// conflict unswizzled (SQ_LDS_BANK_CONFLICT == 512*6144 exactly); now 0.
__global__ __launch_bounds__(512, 4) void fusedScanK(const float* __restrict__ fm,
                                                     float* __restrict__ S) {
    __shared__ float tile[2][CB][260];   // 260 pad: 16B-aligned rows
    const int t = threadIdx.x, lane = t & 63, w = t >> 6;   // w = wave 0..7
    const int cb = blockIdx.x;           // channel block (32 ch)
    const int c0 = cb * CB;
    const int k  = blockIdx.y;
    const int y0 = k * YC;

    const int cg = t & 7;                // store: 4-channel group (8 groups = 32 ch)
    const int x8 = t >> 3;               // store: x mod 64
    const float4 z4 = make_float4(0.f, 0.f, 0.f, 0.f);

    if (k == 0) {                        // y=0 border row, x=0..255 (x=256 never read)
        #pragma unroll
        for (int it = 0; it < 4; ++it) {
            const int lin = it * 512 + t;
            const int cgg = lin & 7, x = lin >> 3;
            ntst4(S + SIDX(cb, 0, x) + 4 * cgg, z4);
        }
    }

    float4 cur[4], nxt[4];
    #pragma unroll
    for (int j = 0; j < 4; ++j)
        cur[j] = *(const float4*)(fm + ((size_t)(c0 + w * 4 + j) << 16)
                                     + (size_t)y0 * 256 + 4 * lane);

    float4 acc[4];
    #pragma unroll
    for (int m = 0; m < 4; ++m) acc[m] = z4;

    const int wcol = (4 * lane) ^ (4 * w);   // swizzled write column
    const int rxor = 4 * cg;                 // swizzle key for reads (row>>2 == cg)

    for (int y = 0; y < YC; ++y) {
        const int buf = y & 1;
        if (y < YC - 1) {                // prefetch next row-block (stays in
            #pragma unroll               //  flight across the raw barrier)
            for (int j = 0; j < 4; ++j)
                nxt[j] = *(const float4*)(fm + ((size_t)(c0 + w * 4 + j) << 16)
                                             + (size_t)(y0 + y + 1) * 256 + 4 * lane);
        }
        // row scan: wave w handles channels w*4..w*4+3, full 256-x per row
        #pragma unroll
        for (int j = 0; j < 4; ++j) {
            const float4 v = cur[j];
            const float local = ((v.x + v.y) + v.z) + v.w;
            float s = local;
            #pragma unroll
            for (int d = 1; d < 64; d <<= 1) {
                float u = __shfl_up(s, d, 64);
                if (lane >= d) s += u;
            }
            const float e = s - local;   // exclusive lane prefix
            float4 p;
            p.x = e   + v.x;
            p.y = p.x + v.y;
            p.z = p.y + v.z;
            p.w = p.z + v.w;
            *(float4*)&tile[buf][w * 4 + j][wcol] = p;
        }
        BAR();
        // col-accumulate + store: per wave, 8 consecutive x * 128B = 1KB
        // contiguous per nt-store; block's 8 rows one dense 263KB region.
        const size_t rowb = SIDX(cb, y0 + y + 1, 0);
        #pragma unroll
        for (int m = 0; m < 4; ++m) {
            const int x = x8 + 64 * m;
            const int xs = x ^ rxor;     // swizzled read column (same for all 4 rows)
            float4 a = acc[m];
            a.x += tile[buf][4 * cg + 0][xs];
            a.y += tile[buf][4 * cg + 1][xs];
            a.z += tile[buf][4 * cg + 2][xs];
            a.w += tile[buf][4 * cg + 3][xs];
            acc[m] = a;
            ntst4(S + rowb + (size_t)(x + 1) * CB + 4 * cg, a);
        }
        if (t < 8)                       // x=0 border for this row (128B)
            ntst4(S + rowb + 4 * t, z4);
        #pragma unroll
        for (int j = 0; j < 4; ++j) cur[j] = nxt[j];
        // no second barrier: next y writes the other LDS buffer; y+2's reuse
        // of this buffer is ordered by the y+1 barrier (lgkmcnt(0) there
        // drains this wave's reads before it signals).
    }
}

// ---------------- offsetK: fp64 prefix of chunk totals ---------------------
// OP'[cb][k][x][32], k=0..32; OP[0]=OP[1]=0; OP[k>=2] = sum of chunk totals
// 0..k-2. Chunk j total = S'[cb][8(j+1)][x][..] (last local row of chunk j).
__global__ __launch_bounds__(256) void offsetK(const float* __restrict__ S,
                                               float* __restrict__ OP) {
    const int gid = blockIdx.x * 256 + threadIdx.x;   // 0 .. 131583 exactly
    const int cc = gid & 31;
    const int xr = gid >> 5;           // 0..4111
    const int x  = xr % SP;            // 0..256
    const int cb = xr / SP;            // 0..15
    OP[OPIDX(cb, 0, x) + cc] = 0.0f;
    OP[OPIDX(cb, 1, x) + cc] = 0.0f;
    double run = 0.0;
    #pragma unroll
    for (int j = 0; j < NK - 1; ++j) {
        run += (double)S[SIDX(cb, YC * (j + 1), x) + cc];
        OP[OPIDX(cb, j + 2, x) + cc] = (float)run;
    }
}

// ---------------- gatherK: per-ROI 9-corner gather with offset add ---------
__global__ __launch_bounds__(256) void gatherK(const float* __restrict__ S,
                                              const float* __restrict__ OP,
                                              const float* __restrict__ roi,
                                              float* __restrict__ out,
                                              float* __restrict__ maskOut,
                                              int N) {
    const int n = blockIdx.x;
    const float xmin = roi[4 * n + 0];
    const float ymin = roi[4 * n + 1];
    const float xmax = roi[4 * n + 2];
    const float ymax = roi[4 * n + 3];

    // Replicate np fp32 op order exactly (no fma contraction).
    const float wsv = __fdiv_rn(__fsub_rn(xmax, xmin), 2.0f);
    const float hsv = __fdiv_rn(__fsub_rn(ymax, ymin), 2.0f);
    const float ax1 = __fadd_rn(xmin, wsv);
    const float ay1 = __fadd_rn(ymin, hsv);
    const float lim = (float)(WD - 1);

    int rx[3], ry[3];
    rx[0] = (int)fminf(fmaxf(rintf(xmin), 0.0f), lim);
    rx[1] = (int)fminf(fmaxf(rintf(ax1), 0.0f), lim);
    rx[2] = (int)fminf(fmaxf(rintf(__fadd_rn(ax1, wsv)), 0.0f), lim);
    ry[0] = (int)fminf(fmaxf(rintf(ymin), 0.0f), lim);
    ry[1] = (int)fminf(fmaxf(rintf(ay1), 0.0f), lim);
    ry[2] = (int)fminf(fmaxf(rintf(__fadd_rn(ay1, hsv)), 0.0f), lim);

    const int t = threadIdx.x;            // c-pair: channels 2t, 2t+1
    const int cbb = t >> 4;               // channel block 0..15
    const int cc  = (t & 15) * 2;         // within-block channel 0..30 (even)
    float2 g[3][3];
    #pragma unroll
    for (int j = 0; j < 3; ++j) {
        const int kk = (ry[j] + YC - 1) >> 3;   // chunk-offset row in OP
        #pragma unroll
        for (int i = 0; i < 3; ++i) {
            const float2 l = *(const float2*)(S  + SIDX(cbb, ry[j], rx[i]) + cc);
            const float2 o = *(const float2*)(OP + OPIDX(cbb, kk, rx[i]) + cc);
            g[j][i] = make_float2(l.x + o.x, l.y + o.y);
        }
    }

    float m[4];
    #pragma unroll
    for (int p = 0; p < 4; ++p) {
        const int ix = p & 1, iy = p >> 1;
        const int cw = rx[ix + 1] - rx[ix];
        const int ch = ry[iy + 1] - ry[iy];
        const int maskv = (cw >= 1 && ch >= 1) ? 1 : 0;
        int areai = cw * ch; if (areai < 1) areai = 1;
        const float areaf = (float)areai;
        const float maskf = (float)maskv;
        m[p] = maskf;

        const float2 s11 = g[iy + 1][ix + 1];
        const float2 s01 = g[iy][ix + 1];
        const float2 s10 = g[iy + 1][ix];
        const float2 s00 = g[iy][ix];
        float2 o;  // reference order: ((S11 - S01) - S10) + S00, /area, *mask
        o.x = __fdiv_rn(((s11.x - s01.x) - s10.x) + s00.x, areaf) * maskf;
        o.y = __fdiv_rn(((s11.y - s01.y) - s10.y) + s00.y, areaf) * maskf;
        *(float2*)(out + ((size_t)p * N + n) * CHN + 2 * t) = o;
    }
    if (t < 4) maskOut[(size_t)t * N + n] = m[t];
}

// ---------------------------------------------------------------------------
extern "C" void kernel_launch(void* const* d_in, const int* in_sizes, int n_in,
                              void* d_out, int out_size, void* d_ws, size_t ws_size,
                              hipStream_t stream) {
    const float* fm  = (const float*)d_in[0];
    const float* roi = (const float*)d_in[1];
    // d_in[2] = patch_num (always 4 here); pe=2 hardcoded.

    const int N = in_sizes[1] / 4;     // 4096
    const int B = 4 * N;               // 16384

    float* S  = (float*)d_ws;
    float* OP = (float*)d_ws + OP_OFF;
    float* out     = (float*)d_out;
    float* maskOut = out + (size_t)B * CHN;

    dim3 gF(CHN / CB, NK);             // 16 x 32 = 512 blocks, 2/CU
    fusedScanK<<<gF, 512, 0, stream>>>(fm, S);

    offsetK<<<(16 * SP * CB) / 256, 256, 0, stream>>>(S, OP);   // 514 blocks

    gatherK<<<N, 256, 0, stream>>>(S, OP, roi, out, maskOut, N);
}

// Round 8
// 246.576 us; speedup vs baseline: 1.1536x; 1.0953x over previous
//
#include <hip/hip_runtime.h>

// RoiPooling via integral image — CHANNEL-GROUP PIPELINED (round 8).
// G=2 groups of 256 channels. Per group g: fusedScanK -> offsetK -> gatherK,
// all reusing ONE S-slice (67.6 MB) + OP-slice (8.7 MB) that fit the 256 MB
// Infinity Cache. Rationale: rounds 1-7 falsified every CU-side and
// HBM-pattern lever for the scan (flat 2.3-2.4 TB/s vs 6.4 TB/s pure-write
// fill). The untested regime: S's 132 MB HBM write round-trip. With a reused
// L3-resident slice, group 1's stores overwrite group 0's dirty lines IN L3
// (no writeback except the final ~68 MB lazy drain), and the tail reads a
// cache-hot slice. fm loads are non-temporal so the 134 MB stream doesn't
// evict the slice. Arithmetic/op order untouched -> output bit-identical.
//
// ws layout (floats):
//   S  @ 0         size 8*257*257*32 = 16,908,544  (67.6 MB)  [per-group slice]
//   OP @ 16908544  size 8*33*257*32  =  2,171,136  ( 8.7 MB)  [per-group slice]

#define CHN 512
#define WD  256
#define SP  257
#define YC  8                 // rows per y-chunk
#define NK  32                // number of y-chunks
#define CB  32                // channels per cb-block / innermost S dim
#define GCH 256               // channels per group
#define SLICE_OFF 16908544UL

#define SIDX(cb, y, x)   ((((size_t)(cb) * SP + (y)) * SP + (x)) * CB)
#define OPIDX(cb, kk, x) ((((size_t)(cb) * 33 + (kk)) * SP + (x)) * CB)

typedef float f32x4v __attribute__((ext_vector_type(4)));

__device__ __forceinline__ float4 ntld4(const float* p) {   // streaming load
    f32x4v u = __builtin_nontemporal_load((const f32x4v*)p);
    return make_float4(u.x, u.y, u.z, u.w);
}

// Raw barrier: LDS-drain only, NO vmcnt(0) (keeps prefetch loads + S stores
// in flight across y-steps). lgkmcnt(0) drains this wave's ds_writes
// (producer visibility) and ds_reads (WAR safety for y+2 buffer reuse).
// Trailing empty asm stops LLVM hoisting post-barrier LDS reads.
#define BAR() do { asm volatile("s_waitcnt lgkmcnt(0)" ::: "memory"); \
                   __builtin_amdgcn_s_barrier(); \
                   asm volatile("" ::: "memory"); } while (0)

// ---------------- fused scan: fm-group -> S-slice (chunk-local integral) ---
// Block 512 thr (8 waves); tile = 32 c x 256 x x 8 y. Grid (8 cb, 32 k) =
// 256 blocks (1/CU, 8 waves/CU — round-0/1 data says occupancy is a ~6%
// effect here, not the limiter). fm base is pre-offset by the group.
// LDS XOR swizzle col ^= 4*(row>>2): unswizzled store-phase reads were a
// deterministic 4-way bank conflict (== 512*6144 exactly); swizzled: 0.
__global__ __launch_bounds__(512, 4) void fusedScanK(const float* __restrict__ fm,
                                                     float* __restrict__ S) {
    __shared__ float tile[2][CB][260];   // 260 pad: 16B-aligned rows
    const int t = threadIdx.x, lane = t & 63, w = t >> 6;   // w = wave 0..7
    const int cb = blockIdx.x;           // cb-block within group, 0..7
    const int c0 = cb * CB;              // channel offset within group
    const int k  = blockIdx.y;
    const int y0 = k * YC;

    const int cg = t & 7;                // store: 4-channel group (8 groups = 32 ch)
    const int x8 = t >> 3;               // store: x mod 64
    const float4 z4 = make_float4(0.f, 0.f, 0.f, 0.f);

    if (k == 0) {                        // y=0 border row, x=0..255 (x=256 never read)
        #pragma unroll
        for (int it = 0; it < 4; ++it) {
            const int lin = it * 512 + t;
            const int cgg = lin & 7, x = lin >> 3;
            *(float4*)(S + SIDX(cb, 0, x) + 4 * cgg) = z4;
        }
    }

    float4 cur[4], nxt[4];
    #pragma unroll
    for (int j = 0; j < 4; ++j)
        cur[j] = ntld4(fm + ((size_t)(c0 + w * 4 + j) << 16)
                          + (size_t)y0 * 256 + 4 * lane);

    float4 acc[4];
    #pragma unroll
    for (int m = 0; m < 4; ++m) acc[m] = z4;

    const int wcol = (4 * lane) ^ (4 * w);   // swizzled write column
    const int rxor = 4 * cg;                 // swizzle key for reads (row>>2 == cg)

    for (int y = 0; y < YC; ++y) {
        const int buf = y & 1;
        if (y < YC - 1) {                // prefetch next row-block (stays in
            #pragma unroll               //  flight across the raw barrier)
            for (int j = 0; j < 4; ++j)
                nxt[j] = ntld4(fm + ((size_t)(c0 + w * 4 + j) << 16)
                                  + (size_t)(y0 + y + 1) * 256 + 4 * lane);
        }
        // row scan: wave w handles channels w*4..w*4+3, full 256-x per row
        #pragma unroll
        for (int j = 0; j < 4; ++j) {
            const float4 v = cur[j];
            const float local = ((v.x + v.y) + v.z) + v.w;
            float s = local;
            #pragma unroll
            for (int d = 1; d < 64; d <<= 1) {
                float u = __shfl_up(s, d, 64);
                if (lane >= d) s += u;
            }
            const float e = s - local;   // exclusive lane prefix
            float4 p;
            p.x = e   + v.x;
            p.y = p.x + v.y;
            p.z = p.y + v.z;
            p.w = p.z + v.w;
            *(float4*)&tile[buf][w * 4 + j][wcol] = p;
        }
        BAR();
        // col-accumulate + store: per wave, 8 consecutive x * 128B = 1KB
        // contiguous; allocating stores (we WANT the slice resident in L3).
        const size_t rowb = SIDX(cb, y0 + y + 1, 0);
        #pragma unroll
        for (int m = 0; m < 4; ++m) {
            const int x = x8 + 64 * m;
            const int xs = x ^ rxor;     // swizzled read column (same for all 4 rows)
            float4 a = acc[m];
            a.x += tile[buf][4 * cg + 0][xs];
            a.y += tile[buf][4 * cg + 1][xs];
            a.z += tile[buf][4 * cg + 2][xs];
            a.w += tile[buf][4 * cg + 3][xs];
            acc[m] = a;
            *(float4*)(S + rowb + (size_t)(x + 1) * CB + 4 * cg) = a;
        }
        if (t < 8)                       // x=0 border for this row (128B)
            *(float4*)(S + rowb + 4 * t) = z4;
        #pragma unroll
        for (int j = 0; j < 4; ++j) cur[j] = nxt[j];
        // no second barrier: next y writes the other LDS buffer; y+2's reuse
        // of this buffer is ordered by the y+1 barrier (lgkmcnt(0) there
        // drains this wave's reads before it signals).
    }
}

// ---------------- offsetK: fp64 prefix of chunk totals (per group) ---------
// OP[cb][k][x][32], cb 0..7, k=0..32; OP[0]=OP[1]=0; OP[k>=2] = sum of chunk
// totals 0..k-2. Chunk j total = S[cb][8(j+1)][x][..].
__global__ __launch_bounds__(256) void offsetK(const float* __restrict__ S,
                                               float* __restrict__ OP) {
    const int gid = blockIdx.x * 256 + threadIdx.x;   // 0 .. 65791 exactly
    const int cc = gid & 31;
    const int xr = gid >> 5;           // 0..2055
    const int x  = xr % SP;            // 0..256
    const int cb = xr / SP;            // 0..7
    OP[OPIDX(cb, 0, x) + cc] = 0.0f;
    OP[OPIDX(cb, 1, x) + cc] = 0.0f;
    double run = 0.0;
    #pragma unroll
    for (int j = 0; j < NK - 1; ++j) {
        run += (double)S[SIDX(cb, YC * (j + 1), x) + cc];
        OP[OPIDX(cb, j + 2, x) + cc] = (float)run;
    }
}

// ---------------- gatherK: per-ROI 9-corner gather (group slice) -----------
// 256 thr = 2 ROIs x 128 thr (one group = 256 channels = 128 c-pairs).
// out is pre-offset by the group's channel base; grid 2048.
__global__ __launch_bounds__(256) void gatherK(const float* __restrict__ S,
                                              const float* __restrict__ OP,
                                              const float* __restrict__ roi,
                                              float* __restrict__ out,
                                              float* __restrict__ maskOut,
                                              int N, int writeMask) {
    const int t = threadIdx.x;
    const int tl = t & 127;               // c-pair within group: channels 2tl, 2tl+1
    const int n = blockIdx.x * 2 + (t >> 7);
    const float xmin = roi[4 * n + 0];
    const float ymin = roi[4 * n + 1];
    const float xmax = roi[4 * n + 2];
    const float ymax = roi[4 * n + 3];

    // Replicate np fp32 op order exactly (no fma contraction).
    const float wsv = __fdiv_rn(__fsub_rn(xmax, xmin), 2.0f);
    const float hsv = __fdiv_rn(__fsub_rn(ymax, ymin), 2.0f);
    const float ax1 = __fadd_rn(xmin, wsv);
    const float ay1 = __fadd_rn(ymin, hsv);
    const float lim = (float)(WD - 1);

    int rx[3], ry[3];
    rx[0] = (int)fminf(fmaxf(rintf(xmin), 0.0f), lim);
    rx[1] = (int)fminf(fmaxf(rintf(ax1), 0.0f), lim);
    rx[2] = (int)fminf(fmaxf(rintf(__fadd_rn(ax1, wsv)), 0.0f), lim);
    ry[0] = (int)fminf(fmaxf(rintf(ymin), 0.0f), lim);
    ry[1] = (int)fminf(fmaxf(rintf(ay1), 0.0f), lim);
    ry[2] = (int)fminf(fmaxf(rintf(__fadd_rn(ay1, hsv)), 0.0f), lim);

    const int cbb = tl >> 4;              // cb-block within group 0..7
    const int cc  = (tl & 15) * 2;        // within-block channel 0..30 (even)
    float2 g[3][3];
    #pragma unroll
    for (int j = 0; j < 3; ++j) {
        const int kk = (ry[j] + YC - 1) >> 3;   // chunk-offset row in OP
        #pragma unroll
        for (int i = 0; i < 3; ++i) {
            const float2 l = *(const float2*)(S  + SIDX(cbb, ry[j], rx[i]) + cc);
            const float2 o = *(const float2*)(OP + OPIDX(cbb, kk, rx[i]) + cc);
            g[j][i] = make_float2(l.x + o.x, l.y + o.y);
        }
    }

    float m[4];
    #pragma unroll
    for (int p = 0; p < 4; ++p) {
        const int ix = p & 1, iy = p >> 1;
        const int cw = rx[ix + 1] - rx[ix];
        const int ch = ry[iy + 1] - ry[iy];
        const int maskv = (cw >= 1 && ch >= 1) ? 1 : 0;
        int areai = cw * ch; if (areai < 1) areai = 1;
        const float areaf = (float)areai;
        const float maskf = (float)maskv;
        m[p] = maskf;

        const float2 s11 = g[iy + 1][ix + 1];
        const float2 s01 = g[iy][ix + 1];
        const float2 s10 = g[iy + 1][ix];
        const float2 s00 = g[iy][ix];
        float2 o;  // reference order: ((S11 - S01) - S10) + S00, /area, *mask
        o.x = __fdiv_rn(((s11.x - s01.x) - s10.x) + s00.x, areaf) * maskf;
        o.y = __fdiv_rn(((s11.y - s01.y) - s10.y) + s00.y, areaf) * maskf;
        *(float2*)(out + ((size_t)p * N + n) * CHN + 2 * tl) = o;
    }
    if (writeMask && tl < 4) maskOut[(size_t)tl * N + n] = m[tl];
}

// ---------------------------------------------------------------------------
extern "C" void kernel_launch(void* const* d_in, const int* in_sizes, int n_in,
                              void* d_out, int out_size, void* d_ws, size_t ws_size,
                              hipStream_t stream) {
    const float* fm  = (const float*)d_in[0];
    const float* roi = (const float*)d_in[1];
    // d_in[2] = patch_num (always 4 here); pe=2 hardcoded.

    const int N = in_sizes[1] / 4;     // 4096
    const int B = 4 * N;               // 16384

    float* S  = (float*)d_ws;
    float* OP = (float*)d_ws + SLICE_OFF;
    float* out     = (float*)d_out;
    float* maskOut = out + (size_t)B * CHN;

    // Two channel groups, same slice buffers; stream order serializes
    // scan(g) -> offset(g) -> gather(g) -> scan(g+1) (buffer reuse safe).
    for (int g = 0; g < 2; ++g) {
        const float* fm_g = fm + ((size_t)(g * GCH) << 16);
        dim3 gF(GCH / CB, NK);             // 8 x 32 = 256 blocks
        fusedScanK<<<gF, 512, 0, stream>>>(fm_g, S);

        offsetK<<<(8 * SP * CB) / 256, 256, 0, stream>>>(S, OP);  // 257 blocks

        gatherK<<<N / 2, 256, 0, stream>>>(S, OP, roi,
                                           out + (size_t)g * GCH, maskOut,
                                           N, g == 0 ? 1 : 0);
    }
}